// Round 6
// baseline (915.803 us; speedup 1.0000x reference)
//
#include <hip/hip_runtime.h>
#include <hip/hip_bf16.h>

// A/B MEASUREMENT ROUND.
// R5 probe found the 3-pass streaming kernel runs at only 4.6 TB/s effective
// (3.45 TB/s HBM), far below the 6.3 TB/s copy ceiling and the harness fills'
// 6.4 TB/s. Suspects: (1) NT-store/vmcnt pass-serialization (VGPR=12 forced
// the compiler to serialize passes; each pass's loads wait behind prior NT
// stores in the vmcnt FIFO), (2) NT stores intrinsically slower than cached
// stores (no L2 write path).
// This round launches TWO visible probe dispatches back-to-back:
//   A: 3-pass, all 6 loads hoisted before any store, NT stores.
//   B: identical, plain cached stores.
// Both compute the real in->out pass, so the final output is correct.

typedef float f32x4 __attribute__((ext_vector_type(4)));

__device__ __forceinline__ float silu_fast(float x) {
    const float LOG2E = 1.4426950408889634f;
    float t = __builtin_amdgcn_exp2f(-x * LOG2E);
    return x * __builtin_amdgcn_rcpf(1.0f + t);
}

__device__ __forceinline__ f32x4 silu4(f32x4 v) {
    f32x4 r;
    r.x = silu_fast(v.x);
    r.y = silu_fast(v.y);
    r.z = silu_fast(v.z);
    r.w = silu_fast(v.w);
    return r;
}

template <bool NT>
__global__ void __launch_bounds__(256)
silu_probe3(const f32x4* __restrict__ in0, f32x4* __restrict__ out0,
            const f32x4* __restrict__ in1, f32x4* __restrict__ out1,
            const f32x4* __restrict__ in2, f32x4* __restrict__ out2) {
    long long base = (long long)blockIdx.x * 512 + threadIdx.x;
    // Hoist ALL loads before ANY store: no load ever waits behind a store
    // in the vmcnt FIFO.
    f32x4 a0 = in0[base], b0 = in0[base + 256];
    f32x4 a1 = in1[base], b1 = in1[base + 256];
    f32x4 a2 = in2[base], b2 = in2[base + 256];
    f32x4 ra0 = silu4(a0), rb0 = silu4(b0);
    f32x4 ra1 = silu4(a1), rb1 = silu4(b1);
    f32x4 ra2 = silu4(a2), rb2 = silu4(b2);
    if (NT) {
        __builtin_nontemporal_store(ra0, &out0[base]);
        __builtin_nontemporal_store(rb0, &out0[base + 256]);
        __builtin_nontemporal_store(ra1, &out1[base]);
        __builtin_nontemporal_store(rb1, &out1[base + 256]);
        __builtin_nontemporal_store(ra2, &out2[base]);
        __builtin_nontemporal_store(rb2, &out2[base + 256]);
    } else {
        out0[base] = ra0;
        out0[base + 256] = rb0;
        out1[base] = ra1;
        out1[base + 256] = rb1;
        out2[base] = ra2;
        out2[base + 256] = rb2;
    }
}

// Fallback single-pass kernel (used only if ws is unexpectedly small).
__global__ void __launch_bounds__(256)
silu_single(const f32x4* __restrict__ in, f32x4* __restrict__ out) {
    long long base = (long long)blockIdx.x * 512 + threadIdx.x;
    f32x4 a = in[base], b = in[base + 256];
    out[base] = silu4(a);
    out[base + 256] = silu4(b);
}

__global__ void silu_fwd_tail_kernel(const float* __restrict__ in, float* __restrict__ out,
                                     long long start, long long n) {
    long long i = start + (long long)blockIdx.x * blockDim.x + threadIdx.x;
    if (i < n) out[i] = silu_fast(in[i]);
}

extern "C" void kernel_launch(void* const* d_in, const int* in_sizes, int n_in,
                              void* d_out, int out_size, void* d_ws, size_t ws_size,
                              hipStream_t stream) {
    const float* x = (const float*)d_in[0];
    float* out = (float*)d_out;
    long long n = (long long)in_sizes[0];  // 67,108,864
    size_t sz = (size_t)n * sizeof(float); // 256 MiB

    long long n4 = n / 4;
    long long blocks = n4 / 512;           // 32768

    char* ws = (char*)d_ws;
    if (blocks > 0 && ws_size >= 4 * sz) {
        const f32x4* i1 = (const f32x4*)(ws);
        f32x4* o1 = (f32x4*)(ws + sz);
        const f32x4* i2 = (const f32x4*)(ws + 2 * sz);
        f32x4* o2 = (f32x4*)(ws + 3 * sz);
        // A: NT stores, loads hoisted.
        silu_probe3<true><<<(int)blocks, 256, 0, stream>>>(
            (const f32x4*)x, (f32x4*)out, i1, o1, i2, o2);
        // B: cached stores, loads hoisted.
        silu_probe3<false><<<(int)blocks, 256, 0, stream>>>(
            (const f32x4*)x, (f32x4*)out, i1, o1, i2, o2);
    } else if (blocks > 0) {
        silu_single<<<(int)blocks, 256, 0, stream>>>((const f32x4*)x, (f32x4*)out);
    }

    long long done = blocks * 512 * 4;
    long long rem = n - done;
    if (rem > 0) {
        int tgrid = (int)((rem + 255) / 256);
        silu_fwd_tail_kernel<<<tgrid, 256, 0, stream>>>(x, out, done, n);
    }
}

// Round 7
// 703.208 us; speedup vs baseline: 1.3023x; 1.3023x over previous
//
#include <hip/hip_runtime.h>
#include <hip/hip_bf16.h>

// SLOPE-MEASUREMENT ROUND.
// R5/R6 probes showed the 3-pass (6-stream) structure is limited to ~4.5 TB/s
// regardless of NT/cached stores or load hoisting -> the probe's extra streams
// were the confound, and the real 2-stream kernel is still unmeasured.
// This round: launch the REAL single-pass kernel 4x back-to-back (idempotent,
// output correct, 2-stream regime preserved). Headline dur_us ~= base(437) + 3T
// gives T, the true per-launch time, without needing the dispatch to surface
// in the top-5 (which the harness's 163-167us 1-GiB fills monopolize).

typedef float f32x4 __attribute__((ext_vector_type(4)));

__device__ __forceinline__ float silu_fast(float x) {
    const float LOG2E = 1.4426950408889634f;
    float t = __builtin_amdgcn_exp2f(-x * LOG2E);
    return x * __builtin_amdgcn_rcpf(1.0f + t);
}

__device__ __forceinline__ f32x4 silu4(f32x4 v) {
    f32x4 r;
    r.x = silu_fast(v.x);
    r.y = silu_fast(v.y);
    r.z = silu_fast(v.z);
    r.w = silu_fast(v.w);
    return r;
}

// Each block: 512 float4 (two coalesced 256-float4 chunks). Grid exact-fit.
__global__ void __launch_bounds__(256)
silu_fwd_kernel(const f32x4* __restrict__ in, f32x4* __restrict__ out) {
    long long base = (long long)blockIdx.x * 512 + threadIdx.x;
    f32x4 a = in[base];
    f32x4 b = in[base + 256];
    f32x4 ra = silu4(a);
    f32x4 rb = silu4(b);
    out[base] = ra;           // plain cached stores (matches m13 copy structure)
    out[base + 256] = rb;
}

__global__ void silu_fwd_tail_kernel(const float* __restrict__ in, float* __restrict__ out,
                                     long long start, long long n) {
    long long i = start + (long long)blockIdx.x * blockDim.x + threadIdx.x;
    if (i < n) out[i] = silu_fast(in[i]);
}

extern "C" void kernel_launch(void* const* d_in, const int* in_sizes, int n_in,
                              void* d_out, int out_size, void* d_ws, size_t ws_size,
                              hipStream_t stream) {
    const float* x = (const float*)d_in[0];
    float* out = (float*)d_out;
    long long n = (long long)in_sizes[0];  // 67,108,864

    long long n4 = n / 4;
    long long blocks = n4 / 512;           // 32768

    if (blocks > 0) {
        // 4 identical launches: idempotent (same in->out), so output stays
        // correct; headline slope vs the 1x baseline yields per-launch T.
        for (int rep = 0; rep < 4; ++rep) {
            silu_fwd_kernel<<<(int)blocks, 256, 0, stream>>>(
                (const f32x4*)x, (f32x4*)out);
        }
    }

    long long done = blocks * 512 * 4;
    long long rem = n - done;
    if (rem > 0) {
        int tgrid = (int)((rem + 255) / 256);
        silu_fwd_tail_kernel<<<tgrid, 256, 0, stream>>>(x, out, done, n);
    }
}